// Round 13
// baseline (120.699 us; speedup 1.0000x reference)
//
#include <hip/hip_runtime.h>
#include <math.h>

#define NB 8
#define NQ 100
#define NQH 50
#define NCP1 3
#define NC 2
#define HIN 128
#define WIN 128
#define HOUT 512
#define WOUT 512
#define QSTR (HIN * WIN)
#define QBYTES (QSTR * 4)

#if __has_builtin(__builtin_amdgcn_exp2f)
#define EXP2F(x) __builtin_amdgcn_exp2f(x)
#else
#define EXP2F(x) exp2f(x)
#endif
#if __has_builtin(__builtin_amdgcn_rcpf)
#define RCPF(x) __builtin_amdgcn_rcpf(x)
#else
#define RCPF(x) (1.0f / (x))
#endif

__device__ __forceinline__ float bperm(int byteaddr, float v) {
  return __int_as_float(__builtin_amdgcn_ds_bpermute(byteaddr, __float_as_int(v)));
}

typedef unsigned int u32x4 __attribute__((ext_vector_type(4)));

// R25 = R24 with the missing stage-0 refill restored.  R24 FAILED with
// absmax 2.0: preload fills stages 0-7 with q=0..7, prologue consumes
// stage0 (q=0), but R24 dropped R21/R23's "LOADSET(0, 8)" -> body7 read
// stale q=0 data as q=8 (error ~2 x max|dsigma| = 2.0, both q-halves) and
// the vmem in-flight count ran 14 not 16 (body0's vmcnt(14) became a
// no-op).  One line restores both invariants; lgkm ledger re-verified
// body-by-body (bodies 0..49 retire exactly what they consume).
// Theory unchanged (R24): every prior variant kept ~130cy of same-body
// LDS round-trip whose wait the COMPILER placed; vmcnt was hand-counted
// since R12 but lgkmcnt never.  All 6 lgkm ops/body are asm volatile
// (ordered, invisible to compiler waitcnt); body s issues bperm(s+1)+pd(s),
// waits lgkmcnt(2) to retire body s-1's 6 ops (full-body shadow), then
// gathers(s) + acc(s-1).  Even/odd register sets, no roll movs.
// Predict 44 -> 28-35us; NULL -> declare structural floor.
__global__ __launch_bounds__(512, 4)
void m2f_fused(const float* __restrict__ cls,
               const float* __restrict__ masks,
               float* __restrict__ out) {
  const int b   = blockIdx.x;   // 0..7   (batch -> XCD under %8 round-robin)
  const int k   = blockIdx.y;   // 0..127 (row group)
  const int tid = threadIdx.x;  // 0..511

  __shared__ float  sigtab[4096];     // sigma(t_i), t_i = i/128 - 16
  __shared__ float2 pq[NQ];           // (p_class0, p_class1) per q
  __shared__ float  part[8][256];     // qh=1 partials: [acc][r*64+lane]

  // ---- sigma table: sig(t) = 1/(1+2^t), nearest-neighbor ----
#pragma unroll
  for (int j = 0; j < 8; ++j) {
    const int i = tid + j * 512;
    const float x = (float)i * 0.0078125f - 16.0f;
    sigtab[i] = RCPF(1.0f + EXP2F(x));
  }

  // ---- inline class softmax (keep first NC of NCP1) ----
  if (tid < NQ) {
    const float* cl = cls + (b * NQ + tid) * NCP1;
    float a0 = cl[0], a1 = cl[1], a2 = cl[2];
    float mx = fmaxf(a0, fmaxf(a1, a2));
    const float L2E = 1.4426950408889634f;
    float e0 = EXP2F((a0 - mx) * L2E);
    float e1 = EXP2F((a1 - mx) * L2E);
    float e2 = EXP2F((a2 - mx) * L2E);
    float inv = RCPF(e0 + e1 + e2);
    pq[tid] = make_float2(e0 * inv, e1 * inv);
  }
  __syncthreads();   // drains vmcnt+lgkmcnt: counters are ZERO entering loop

  const int wave = tid >> 6;    // 0..7
  const int r    = wave & 3;    // output row phase (y = 4k+r)
  const int qh   = wave >> 2;   // q half: 0 -> q 0..49, 1 -> q 50..99
  const int lane = tid & 63;    // col group: x = 8*lane .. 8*lane+7
  const int q0   = qh * NQH;

  // LDS byte offsets (group-segment aperture is 4GB-aligned: low 32 bits
  // of a flat shared address == the LDS offset)
  const unsigned tabb = (unsigned)(size_t)&sigtab[0];
  const unsigned pqb  = (unsigned)(size_t)&pq[0];

  const int rlo = (r < 2) ? (k > 0 ? k - 1 : 0) : k;
  const int rhi = (r < 2) ? k : (k < HIN - 1 ? k + 1 : HIN - 1);
  const float NL2E128 = -1.4426950408889634f * 128.0f;
  const float wlo = ((r == 0) ? 0.375f : (r == 1) ? 0.125f
                   : (r == 2) ? 0.875f : 0.625f) * NL2E128;
  const float whi = ((r == 0) ? 0.625f : (r == 1) ? 0.875f
                   : (r == 2) ? 0.125f : 0.375f) * NL2E128;

  // buffer SRD over THIS batch's masks window (bounds-checked loads)
  union { const float* p; unsigned long long u; } pn;
  pn.p = masks + (size_t)b * NQ * QSTR;
  u32x4 srd;
  srd.x = (unsigned int)pn.u;
  srd.y = (unsigned int)(pn.u >> 32) & 0xFFFFu;  // stride=0
  srd.z = (unsigned int)(NQ * QSTR * 4);         // num_records (bytes)
  srd.w = 0x00020000u;                           // raw dword access

  const int voffA = q0 * QBYTES + (rlo * WIN + 2 * lane) * 4;
  const int voffB = q0 * QBYTES + (rhi * WIN + 2 * lane) * 4;

  const int addrL = (lane - 1) << 2;
  const int addrR = (lane + 1) << 2;
  const bool edgeL = (lane == 0);
  const bool edgeR = (lane == 63);

  // accumulators: Sum_q pd * sigma at {mid-left, u0, mid, u1}
  float2 aSL = make_float2(0.f, 0.f);
  float2 aS0 = make_float2(0.f, 0.f);
  float2 aSM = make_float2(0.f, 0.f);
  float2 aS1 = make_float2(0.f, 0.f);

  // depth-8 vmem stages + even/odd DS pipeline sets
  float2 A0, B0, A1, B1, A2, B2, A3, B3, A4, B4, A5, B5, A6, B6, A7, B7;
  float  u0E, u1E, uLrE, sgE0, sgE1, sgE2, sgE3;
  float  u0O, u1O, uLrO, sgO0, sgO1, sgO2, sgO3;
  float2 pdE, pdO;

#define LOADSET(S, qrel)                                                  \
  do {                                                                    \
    asm volatile("buffer_load_dwordx2 %0, %2, %3, 0 offen\n\t"            \
                 "buffer_load_dwordx2 %1, %4, %3, 0 offen"                \
                 : "=&v"(A##S), "=&v"(B##S)                               \
                 : "v"(voffA + (qrel) * QBYTES), "s"(srd),                \
                   "v"(voffB + (qrel) * QBYTES));                         \
  } while (0)

#define WT(S, N)                                                          \
  asm volatile("s_waitcnt vmcnt(" #N ")" : "+v"(A##S), "+v"(B##S))

  // raw DS ops (asm volatile: ordered among themselves, invisible to the
  // compiler's waitcnt insertion -> our counts are exact)
#define DSR32(dst, addr)                                                  \
  asm volatile("ds_read_b32 %0, %1" : "=v"(dst) : "v"(addr))
#define DSR64(dst, addr)                                                  \
  asm volatile("ds_read_b64 %0, %1" : "=v"(dst) : "v"(addr))
#define BPERMA(dst, src)                                                  \
  asm volatile("ds_bpermute_b32 %0, %1, %2"                               \
               : "=v"(dst) : "v"(addrL), "v"(src))

  // table address: u already = 128*t + 2048.5
#define SIGA(u)                                                           \
  (tabb + (((unsigned)(int)fminf(fmaxf((u), 0.0f), 4095.0f)) << 2))

  // steady wait: retire prev body's 6 DS ops (ours +2 just issued in flight)
#define LGKMW6(C, X)                                                      \
  do {                                                                    \
    asm volatile("s_waitcnt lgkmcnt(2)"                                   \
                 : "+v"(uLr##C), "+v"(pd##X), "+v"(sg##X##0),             \
                   "+v"(sg##X##1), "+v"(sg##X##2), "+v"(sg##X##3));       \
    __builtin_amdgcn_sched_barrier(0);                                    \
  } while (0)

#define ACC(X)                                                            \
  do {                                                                    \
    aSL.x = fmaf(pd##X.x, sg##X##0, aSL.x);                               \
    aSL.y = fmaf(pd##X.y, sg##X##0, aSL.y);                               \
    aS0.x = fmaf(pd##X.x, sg##X##1, aS0.x);                               \
    aS0.y = fmaf(pd##X.y, sg##X##1, aS0.y);                               \
    aSM.x = fmaf(pd##X.x, sg##X##2, aSM.x);                               \
    aSM.y = fmaf(pd##X.y, sg##X##2, aSM.y);                               \
    aS1.x = fmaf(pd##X.x, sg##X##3, aS1.x);                               \
    aS1.y = fmaf(pd##X.y, sg##X##3, aS1.y);                               \
  } while (0)

#define MIDG(C)                                                           \
  do {                                                                    \
    float uL  = edgeL ? u0##C : uLr##C;                                   \
    float um  = 0.5f * (u0##C + u1##C);                                   \
    float umL = 0.5f * (uL + u0##C);                                      \
    DSR32(sg##C##0, SIGA(umL));                                           \
    DSR32(sg##C##1, SIGA(u0##C));                                         \
    DSR32(sg##C##2, SIGA(um));                                            \
    DSR32(sg##C##3, SIGA(u1##C));                                         \
  } while (0)

  // body s: consume A/B(s+1)->u(X); issue bperm(s+1),pd(s); retire s-1's
  // 6 ops; gathers(s); acc(s-1); refill stage with q=s+9.
#define BODY(ST, C, X, s)                                                 \
  do {                                                                    \
    WT(ST, 14);                                                           \
    u0##X = fmaf(wlo, A##ST.x, fmaf(whi, B##ST.x, 2048.5f));              \
    u1##X = fmaf(wlo, A##ST.y, fmaf(whi, B##ST.y, 2048.5f));              \
    BPERMA(uLr##X, u1##X);                                                \
    DSR64(pd##C, pqb + (unsigned)((q0 + (s)) * 8));                       \
    LGKMW6(C, X);                                                         \
    MIDG(C);                                                              \
    ACC(X);                                                               \
    LOADSET(ST, (s) + 9);                                                 \
  } while (0)

#define BODYNL(ST, VM, C, X, s)                                           \
  do {                                                                    \
    WT(ST, VM);                                                           \
    u0##X = fmaf(wlo, A##ST.x, fmaf(whi, B##ST.x, 2048.5f));              \
    u1##X = fmaf(wlo, A##ST.y, fmaf(whi, B##ST.y, 2048.5f));              \
    BPERMA(uLr##X, u1##X);                                                \
    DSR64(pd##C, pqb + (unsigned)((q0 + (s)) * 8));                       \
    LGKMW6(C, X);                                                         \
    MIDG(C);                                                              \
    ACC(X);                                                               \
  } while (0)

  LOADSET(0, 0); LOADSET(1, 1); LOADSET(2, 2); LOADSET(3, 3);
  LOADSET(4, 4); LOADSET(5, 5); LOADSET(6, 6); LOADSET(7, 7);

  // prologue: u(0) + bperm(0)  [lgkm out: 1]; REFILL stage0 with q=8
  // (the line R24 dropped -- keeps 16 loads in flight and q=8 correct)
  WT(0, 14);
  u0E = fmaf(wlo, A0.x, fmaf(whi, B0.x, 2048.5f));
  u1E = fmaf(wlo, A0.y, fmaf(whi, B0.y, 2048.5f));
  BPERMA(uLrE, u1E);
  LOADSET(0, 8);

  // body 0 (C=E, X=O): no ACC; wait(2) retires bperm(0) [out: 3 -> 2]
  WT(1, 14);
  u0O = fmaf(wlo, A1.x, fmaf(whi, B1.x, 2048.5f));
  u1O = fmaf(wlo, A1.y, fmaf(whi, B1.y, 2048.5f));
  BPERMA(uLrO, u1O);
  DSR64(pdE, pqb + (unsigned)((q0 + 0) * 8));
  asm volatile("s_waitcnt lgkmcnt(2)" : "+v"(uLrE));
  __builtin_amdgcn_sched_barrier(0);
  MIDG(E);
  LOADSET(1, 9);

  // steady: bodies s = 1..40 (5 chunks x 8; stage (s+1)&7, parity s&1)
  for (int q = 1; q < 41; q += 8) {
    BODY(2, O, E, q);
    BODY(3, E, O, q + 1);
    BODY(4, O, E, q + 2);
    BODY(5, E, O, q + 3);
    BODY(6, O, E, q + 4);
    BODY(7, E, O, q + 5);
    BODY(0, O, E, q + 6);
    BODY(1, E, O, q + 7);
  }

  // drain: bodies 41..48, no refills; vmcnt 14,12,...,0
  BODYNL(2, 14, O, E, 41);
  BODYNL(3, 12, E, O, 42);
  BODYNL(4, 10, O, E, 43);
  BODYNL(5, 8,  E, O, 44);
  BODYNL(6, 6,  O, E, 45);
  BODYNL(7, 4,  E, O, 46);
  BODYNL(0, 2,  O, E, 47);
  BODYNL(1, 0,  E, O, 48);

  // body 49 (C=O, X=E): pd(49); retire body48's 6; gathers(49); acc(48);
  // retire pd(49)+g(49); acc(49)
  DSR64(pdO, pqb + (unsigned)((q0 + 49) * 8));
  asm volatile("s_waitcnt lgkmcnt(1)"
               : "+v"(uLrO), "+v"(pdE), "+v"(sgE0), "+v"(sgE1),
                 "+v"(sgE2), "+v"(sgE3));
  __builtin_amdgcn_sched_barrier(0);
  MIDG(O);
  ACC(E);
  asm volatile("s_waitcnt lgkmcnt(0)"
               : "+v"(pdO), "+v"(sgO0), "+v"(sgO1), "+v"(sgO2), "+v"(sgO3));
  __builtin_amdgcn_sched_barrier(0);
  ACC(O);

  // ---- combine q-halves through LDS (8 floats/col, conflict-free) ----
  const int col = r * 64 + lane;
  if (qh == 1) {
    part[0][col] = aSL.x;  part[1][col] = aSL.y;
    part[2][col] = aS0.x;  part[3][col] = aS0.y;
    part[4][col] = aSM.x;  part[5][col] = aSM.y;
    part[6][col] = aS1.x;  part[7][col] = aS1.y;
  }
  __syncthreads();
  if (qh == 0) {
    aSL.x += part[0][col];  aSL.y += part[1][col];
    aS0.x += part[2][col];  aS0.y += part[3][col];
    aSM.x += part[4][col];  aSM.y += part[5][col];
    aS1.x += part[6][col];  aS1.y += part[7][col];

    // SR = right neighbor's mid-left sum; lane 63: SR = S1
    float SRx_r = bperm(addrR, aSL.x);
    float SRy_r = bperm(addrR, aSL.y);
    float SRx = edgeR ? aS1.x : SRx_r;
    float SRy = edgeR ? aS1.y : SRy_r;

    float o0x = fmaf(0.25f, aS0.x, 0.75f * aSL.x);
    float o1x = fmaf(0.75f, aS0.x, 0.25f * aSL.x);
    float o2x = fmaf(0.25f, aSM.x, 0.75f * aS0.x);
    float o3x = fmaf(0.75f, aSM.x, 0.25f * aS0.x);
    float o4x = fmaf(0.25f, aS1.x, 0.75f * aSM.x);
    float o5x = fmaf(0.75f, aS1.x, 0.25f * aSM.x);
    float o6x = fmaf(0.25f, SRx,   0.75f * aS1.x);
    float o7x = fmaf(0.75f, SRx,   0.25f * aS1.x);
    float o0y = fmaf(0.25f, aS0.y, 0.75f * aSL.y);
    float o1y = fmaf(0.75f, aS0.y, 0.25f * aSL.y);
    float o2y = fmaf(0.25f, aSM.y, 0.75f * aS0.y);
    float o3y = fmaf(0.75f, aSM.y, 0.25f * aS0.y);
    float o4y = fmaf(0.25f, aS1.y, 0.75f * aSM.y);
    float o5y = fmaf(0.75f, aS1.y, 0.25f * aSM.y);
    float o6y = fmaf(0.25f, SRy,   0.75f * aS1.y);
    float o7y = fmaf(0.75f, SRy,   0.25f * aS1.y);

    const int y  = 4 * k + r;
    const int x0 = 8 * lane;
    float* o0 = out + (((size_t)b * NC + 0) * HOUT + y) * WOUT + x0;
    float* o1 = out + (((size_t)b * NC + 1) * HOUT + y) * WOUT + x0;
    *(float4*)o0       = make_float4(o0x, o1x, o2x, o3x);
    *(float4*)(o0 + 4) = make_float4(o4x, o5x, o6x, o7x);
    *(float4*)o1       = make_float4(o0y, o1y, o2y, o3y);
    *(float4*)(o1 + 4) = make_float4(o4y, o5y, o6y, o7y);
  }
}

extern "C" void kernel_launch(void* const* d_in, const int* in_sizes, int n_in,
                              void* d_out, int out_size, void* d_ws, size_t ws_size,
                              hipStream_t stream) {
  const float* cls   = (const float*)d_in[0];   // [8,100,3] fp32
  const float* masks = (const float*)d_in[1];   // [8,100,128,128] fp32
  float* out = (float*)d_out;                   // [8,2,512,512] fp32
  // grid(8,128): linear block id = b + 8*k -> id%8 = b -> one batch per XCD
  dim3 grid(NB, HIN);
  m2f_fused<<<grid, 512, 0, stream>>>(cls, masks, out);
}